// Round 1
// baseline (409.731 us; speedup 1.0000x reference)
//
#include <hip/hip_runtime.h>

// CTC loss forward, B=64 T=1000 V=64 L=150 (S=2L+1=301)
// d_in[0]: logits f32 [B,T,V]; d_in[1]: audio_length i32 [B]; d_in[2]: labels i32 [B,L]
// d_out: scalar f32 (mean loss). d_ws: lse buffer [B*T] f32.

#define NEGV -1e30f
#define VV 64
#define L_MAX 150
#define S_MAX 301   // 2*L_MAX+1

// ---------------- Kernel A: per-frame log-sum-exp over V=64 ----------------
__global__ __launch_bounds__(256) void lse_kernel(const float* __restrict__ logits,
                                                  float* __restrict__ lse,
                                                  float* __restrict__ out,
                                                  int nframes) {
    if (blockIdx.x == 0 && threadIdx.x == 0) out[0] = 0.0f;  // zero accumulator
    int frame = (blockIdx.x * blockDim.x + threadIdx.x) >> 6;
    int lane = threadIdx.x & 63;
    if (frame >= nframes) return;
    float x = logits[(size_t)frame * VV + lane];
    float m = x;
    #pragma unroll
    for (int off = 32; off >= 1; off >>= 1) m = fmaxf(m, __shfl_xor(m, off));
    float s = __expf(x - m);
    #pragma unroll
    for (int off = 32; off >= 1; off >>= 1) s += __shfl_xor(s, off);
    if (lane == 0) lse[frame] = m + __logf(s);
}

// ---------------- Kernel B: forward recursion, one block per example -------
__global__ __launch_bounds__(320) void ctc_kernel(const float* __restrict__ logits,
                                                  const int* __restrict__ audio_len,
                                                  const int* __restrict__ labels,
                                                  const float* __restrict__ lse,
                                                  float* __restrict__ out,
                                                  int B, int T, int L) {
    const int b = blockIdx.x;
    const int tid = threadIdx.x;
    const int S = 2 * L + 1;

    __shared__ float A[2][S_MAX];
    __shared__ float fb[2][VV];
    __shared__ float lsb[2];
    __shared__ int lab_sh[L_MAX];
    __shared__ int cnt_sh[5];
    __shared__ int label_len_sh;

    const float* lg = logits + (size_t)b * T * VV;
    const float* ls = lse + (size_t)b * T;

    // logit_length transform: ll = ceil((audio+1)/128); Tb = ll // 2
    int al = audio_len[b];
    int ll = (al + 128) >> 7;
    int Tb = ll >> 1;
    if (Tb < 1) Tb = 1;
    if (Tb > T) Tb = T;
    const int t_final = Tb - 1;

    // load labels, count valid
    int c = 0;
    if (tid < L) {
        int lv = labels[b * L + tid];
        lab_sh[tid] = lv;
        c = (lv >= 0) ? 1 : 0;
    }
    #pragma unroll
    for (int off = 32; off >= 1; off >>= 1) c += __shfl_xor(c, off);
    if ((tid & 63) == 0) cnt_sh[tid >> 6] = c;
    __syncthreads();
    if (tid == 0)
        label_len_sh = cnt_sh[0] + cnt_sh[1] + cnt_sh[2] + cnt_sh[3] + cnt_sh[4];

    // per-thread state constants: extended symbol + skip-allowed flag
    int ext_s = 0;
    bool skip = false;
    if (tid < S) {
        if (tid & 1) {
            int lv = lab_sh[tid >> 1];
            ext_s = (lv < 0) ? 0 : lv;
        }
        if (tid >= 2 && ext_s != 0) {
            // s odd (ext_s!=0 implies odd): ext[s-2] = lab[(s>>1)-1]
            int lv2 = lab_sh[(tid >> 1) - 1];
            int em2 = (lv2 < 0) ? 0 : lv2;
            skip = (ext_s != em2);
        }
    }

    // init alpha at t=0; stage frame 1
    float lse0 = ls[0];
    if (tid < S) {
        float a;
        if (tid == 0)      a = lg[0] - lse0;       // blank
        else if (tid == 1) a = lg[ext_s] - lse0;   // first label
        else               a = NEGV;
        A[0][tid] = a;
    }
    if (t_final >= 1) {
        if (tid < VV) fb[0][tid] = lg[VV + tid];
        if (tid == VV) lsb[0] = ls[1];
    }
    __syncthreads();

    int cur = 0, pb = 0;
    for (int t = 1; t <= t_final; ++t) {
        // prefetch frame t+1 into registers (overlaps with alpha update)
        float pre = 0.0f, plse = 0.0f;
        const bool do_pre = (t + 1 <= t_final);
        if (do_pre) {
            if (tid < VV) pre = lg[(size_t)(t + 1) * VV + tid];
            if (tid == VV) plse = ls[t + 1];
        }
        if (tid < S) {
            float a0 = A[cur][tid];
            float a1 = (tid >= 1) ? A[cur][tid - 1] : NEGV;
            float a2 = skip ? A[cur][tid - 2] : NEGV;
            float m = fmaxf(fmaxf(a0, a1), a2);
            float sum = __expf(a0 - m) + __expf(a1 - m) + __expf(a2 - m);
            float lp = fb[pb][ext_s] - lsb[pb];
            A[cur ^ 1][tid] = lp + m + __logf(sum);
        }
        if (do_pre) {
            if (tid < VV) fb[pb ^ 1][tid] = pre;
            if (tid == VV) lsb[pb ^ 1] = plse;
        }
        __syncthreads();
        cur ^= 1;
        pb ^= 1;
    }

    if (tid == 0) {
        int llen = label_len_sh;
        int s_last = 2 * llen;
        float ab = A[cur][s_last];
        float al2 = A[cur][(s_last >= 1) ? (s_last - 1) : 0];
        float m = fmaxf(ab, al2);
        float loss = -(m + __logf(__expf(ab - m) + __expf(al2 - m)));
        atomicAdd(out, loss * (1.0f / (float)B));
    }
}

extern "C" void kernel_launch(void* const* d_in, const int* in_sizes, int n_in,
                              void* d_out, int out_size, void* d_ws, size_t ws_size,
                              hipStream_t stream) {
    const float* logits = (const float*)d_in[0];
    const int* audio = (const int*)d_in[1];
    const int* labels = (const int*)d_in[2];
    float* out = (float*)d_out;

    int B = in_sizes[1];
    int L = in_sizes[2] / B;
    int T = in_sizes[0] / (B * VV);

    float* lse = (float*)d_ws;  // B*T floats
    int nframes = B * T;

    lse_kernel<<<(nframes + 3) / 4, 256, 0, stream>>>(logits, lse, out, nframes);
    ctc_kernel<<<B, 320, 0, stream>>>(logits, audio, labels, lse, out, B, T, L);
}

// Round 3
// 286.854 us; speedup vs baseline: 1.4284x; 1.4284x over previous
//
#include <hip/hip_runtime.h>

// CTC loss forward, B=64 T=1000 V=64 L=150 (S=2L+1=301)
// d_in[0]: logits f32 [B,T,V]; d_in[1]: audio_length i32 [B]; d_in[2]: labels i32 [B,L]
// d_out: scalar f32 (mean loss). d_ws: lse buffer [B*T] f32.
//
// Strategy: alpha recursion in EXP domain with fp64 state (708-nat range below
// the running max >> ~400-nat trellis spread), fp32 emissions, one wave per
// example, zero barriers in the main loop. Renorm every 8 steps.

#define VV 64
#define L2E 1.4426950408889634f
#define CH 16

// ---------------- Kernel A: per-frame log-sum-exp over V=64 ----------------
// 16 lanes per frame, each loads float4 (fully coalesced 1KB per wave-load).
__global__ __launch_bounds__(256) void lse_kernel(const float4* __restrict__ lg4,
                                                  float* __restrict__ lse,
                                                  float* __restrict__ out,
                                                  int nframes) {
    if (blockIdx.x == 0 && threadIdx.x == 0) out[0] = 0.0f;  // zero loss accumulator
    int g = blockIdx.x * blockDim.x + threadIdx.x;
    int frame = g >> 4, q = g & 15;
    if (frame >= nframes) return;
    float4 v = lg4[(size_t)frame * 16 + q];
    float m = fmaxf(fmaxf(v.x, v.y), fmaxf(v.z, v.w));
    #pragma unroll
    for (int off = 8; off >= 1; off >>= 1) m = fmaxf(m, __shfl_xor(m, off));
    float s = __expf(v.x - m) + __expf(v.y - m) + __expf(v.z - m) + __expf(v.w - m);
    #pragma unroll
    for (int off = 8; off >= 1; off >>= 1) s += __shfl_xor(s, off);
    if (q == 0) lse[frame] = m + __logf(s);
}

// ---------------- Kernel B: forward recursion, one WAVE per example --------
// Lane holds states [5*lane, 5*lane+4] as fp64; cross-lane via shfl_up;
// emission gathers via ds_bpermute of the frame's 64 logits (one per lane).

#define LOADCHUNK(X, LS, BASE)                                                  \
    do {                                                                        \
        _Pragma("unroll")                                                       \
        for (int k_ = 0; k_ < CH; ++k_) {                                       \
            int tt_ = (BASE) + k_; if (tt_ > tf) tt_ = tf;                      \
            X[k_] = lg[(size_t)tt_ * VV + lane] * L2E;                          \
        }                                                                       \
        { int tt_ = (BASE) + lane; if (tt_ > tf) tt_ = tf;                      \
          LS = ls[tt_] * L2E; }                                                 \
    } while (0)

#define PROCCHUNK(X, LS, BASE)                                                  \
    do {                                                                        \
        _Pragma("unroll")                                                       \
        for (int k_ = 0; k_ < CH; ++k_) {                                       \
            const bool act_ = ((BASE) + k_ <= tf);                              \
            float lse_t = __shfl(LS, k_);                                       \
            int xv_ = __float_as_int(X[k_]);                                    \
            double e_[5];                                                       \
            _Pragma("unroll")                                                   \
            for (int i_ = 0; i_ < 5; ++i_) {                                    \
                float g_ = __int_as_float(                                      \
                    __builtin_amdgcn_ds_bpermute(ext4[i_], xv_));               \
                e_[i_] = (double)__builtin_amdgcn_exp2f(g_ - lse_t);            \
            }                                                                   \
            double pm1_ = __shfl_up(p[4], 1);                                   \
            double pm2_ = __shfl_up(p[3], 1);                                   \
            pm1_ = (lane == 0) ? 0.0 : pm1_;                                    \
            pm2_ = (lane == 0) ? 0.0 : pm2_;                                    \
            double n0_ = e_[0] * (p[0] + pm1_ + skd[0] * pm2_);                 \
            double n1_ = e_[1] * (p[1] + p[0] + skd[1] * pm1_);                 \
            double n2_ = e_[2] * (p[2] + p[1] + skd[2] * p[0]);                 \
            double n3_ = e_[3] * (p[3] + p[2] + skd[3] * p[1]);                 \
            double n4_ = e_[4] * (p[4] + p[3] + skd[4] * p[2]);                 \
            p[0] = act_ ? n0_ : p[0];                                           \
            p[1] = act_ ? n1_ : p[1];                                           \
            p[2] = act_ ? n2_ : p[2];                                           \
            p[3] = act_ ? n3_ : p[3];                                           \
            p[4] = act_ ? n4_ : p[4];                                           \
            if ((k_ & 7) == 7) {                                                \
                if (act_) { /* wave-uniform renorm */                           \
                    double m_ = fmax(fmax(fmax(p[0], p[1]),                     \
                                          fmax(p[2], p[3])), p[4]);             \
                    _Pragma("unroll")                                           \
                    for (int o_ = 32; o_ >= 1; o_ >>= 1)                        \
                        m_ = fmax(m_, __shfl_xor(m_, o_));                      \
                    C += log(m_);                                               \
                    double r_ = 1.0 / m_;                                       \
                    _Pragma("unroll")                                           \
                    for (int i_ = 0; i_ < 5; ++i_) p[i_] *= r_;                 \
                }                                                               \
            }                                                                   \
        }                                                                       \
    } while (0)

__global__ __launch_bounds__(64) void ctc_kernel(const float* __restrict__ lgall,
                                                 const int* __restrict__ audio_len,
                                                 const int* __restrict__ labels,
                                                 const float* __restrict__ lseall,
                                                 float* __restrict__ out,
                                                 int B, int T, int L) {
    const int b = blockIdx.x;
    const int lane = threadIdx.x;
    const int S = 2 * L + 1;
    const float* lg = lgall + (size_t)b * T * VV;
    const float* ls = lseall + (size_t)b * T;

    // logit_length transform: ll = ceil((audio+1)/128); Tb = ll // 2
    int al = audio_len[b];
    int Tb = ((al + 128) >> 7) >> 1;
    if (Tb < 1) Tb = 1;
    if (Tb > T) Tb = T;
    const int tf = Tb - 1;

    // labels -> LDS (once); count valid labels
    __shared__ int lab_sh[160];
    int cnt = 0;
    for (int k = lane; k < L; k += 64) {
        int lv = labels[b * L + k];
        lab_sh[k] = lv;
        cnt += (lv >= 0) ? 1 : 0;
    }
    #pragma unroll
    for (int off = 32; off >= 1; off >>= 1) cnt += __shfl_xor(cnt, off);
    __syncthreads();
    const int llen = cnt;
    const int s_last = 2 * llen;

    // per-state constants: byte-index of symbol for bpermute, skip flag (fp64)
    int ext4[5];
    double skd[5];
    #pragma unroll
    for (int i = 0; i < 5; ++i) {
        int s = lane * 5 + i;
        int sym = 0;
        double sk = 0.0;
        if (s < S && (s & 1)) {
            int lv = lab_sh[s >> 1];
            sym = lv < 0 ? 0 : lv;
            if (s >= 3 && sym != 0) {
                int lv2 = lab_sh[(s >> 1) - 1];
                int s2 = lv2 < 0 ? 0 : lv2;
                sk = (sym != s2) ? 1.0 : 0.0;
            }
        }
        ext4[i] = sym * 4;
        skd[i] = sk;
    }

    // t = 0 init: p[0]=prob(blank), p[1]=prob(label0) on lane 0, rest 0
    double C = 0.0;
    float x0 = lg[lane] * L2E;
    float lse0 = ls[0] * L2E;
    int xi0 = __float_as_int(x0);
    float gb = __int_as_float(__builtin_amdgcn_ds_bpermute(0, xi0));
    float g1 = __int_as_float(__builtin_amdgcn_ds_bpermute(ext4[1], xi0));
    double p[5];
    #pragma unroll
    for (int i = 0; i < 5; ++i) p[i] = 0.0;
    if (lane == 0) {
        p[0] = (double)__builtin_amdgcn_exp2f(gb - lse0);
        p[1] = (double)__builtin_amdgcn_exp2f(g1 - lse0);
    }

    // main loop: double-buffered 16-frame register chunks of logits
    float xA[CH], xB[CH];
    float lA, lB;
    LOADCHUNK(xA, lA, 1);
    int base = 1;
    for (;;) {
        LOADCHUNK(xB, lB, base + CH);
        PROCCHUNK(xA, lA, base);
        if (base + CH > tf) break;
        base += CH;
        LOADCHUNK(xA, lA, base + CH);
        PROCCHUNK(xB, lB, base);
        if (base + CH > tf) break;
        base += CH;
    }

    // readout: states s_last (blank) and s_last-1 (last label)
    double vb = 0.0, vl = 0.0;
    #pragma unroll
    for (int i = 0; i < 5; ++i) {
        int s = lane * 5 + i;
        if (s == s_last) vb = p[i];
        if (s == s_last - 1) vl = p[i];
    }
    #pragma unroll
    for (int off = 32; off >= 1; off >>= 1) {
        vb += __shfl_xor(vb, off);
        vl += __shfl_xor(vl, off);
    }
    if (lane == 0) {
        double loss = -(log(vb + vl) + C);
        atomicAdd(out, (float)(loss * (1.0 / (double)B)));
    }
}

extern "C" void kernel_launch(void* const* d_in, const int* in_sizes, int n_in,
                              void* d_out, int out_size, void* d_ws, size_t ws_size,
                              hipStream_t stream) {
    const float* logits = (const float*)d_in[0];
    const int* audio = (const int*)d_in[1];
    const int* labels = (const int*)d_in[2];
    float* out = (float*)d_out;

    int B = in_sizes[1];
    int L = in_sizes[2] / B;
    int T = in_sizes[0] / (B * VV);

    float* lse = (float*)d_ws;  // B*T floats
    int nframes = B * T;

    int threadsA = nframes * 16;
    lse_kernel<<<(threadsA + 255) / 256, 256, 0, stream>>>((const float4*)logits, lse, out, nframes);
    ctc_kernel<<<B, 64, 0, stream>>>(logits, audio, labels, lse, out, B, T, L);
}

// Round 4
// 191.741 us; speedup vs baseline: 2.1369x; 1.4960x over previous
//
#include <hip/hip_runtime.h>

// CTC loss forward, B=64 T=1000 V=64 L=150 (S=2L+1=301)
// d_in[0]: logits f32 [B,T,V]; d_in[1]: audio_length i32 [B]; d_in[2]: labels i32 [B,L]
// d_out: scalar f32 (mean loss). d_ws: sumlse[B] f64.
//
// fwd/bwd split: wave 0 runs alpha from t=0 to mid, wave 1 runs beta from
// t=Tf down to mid+1; loss from sum_s alpha_mid(s)*beta_mid(s).
// Exp-domain fp64 state, unnormalized emissions e^logit (total lse subtracted
// once at the end), power-of-2 renorm every 32 steps via integer exponent max.

#define VV 64
#define L2E 1.4426950408889634f
#define LN2D 0.6931471805599453
#define CH 8

// ---------------- Kernel A: per-frame lse summed per example ---------------
__global__ __launch_bounds__(256) void lse_kernel(const float4* __restrict__ lg4,
                                                  const int* __restrict__ audio_len,
                                                  double* __restrict__ sumlse,
                                                  float* __restrict__ out,
                                                  int T) {
    if (blockIdx.x == 0 && blockIdx.y == 0 && threadIdx.x == 0) out[0] = 0.0f;
    int b = blockIdx.y;
    int g = blockIdx.x * blockDim.x + threadIdx.x;
    int t = g >> 4, q = g & 15;
    if (t >= T) return;
    int al = audio_len[b];
    int Tb = ((al + 128) >> 7) >> 1;
    if (Tb < 1) Tb = 1;
    if (Tb > T) Tb = T;
    if (t >= Tb) return;                       // frames past Tb never used
    float4 v = lg4[((size_t)b * T + t) * 16 + q];
    float m = fmaxf(fmaxf(v.x, v.y), fmaxf(v.z, v.w));
    #pragma unroll
    for (int off = 8; off >= 1; off >>= 1) m = fmaxf(m, __shfl_xor(m, off));
    float s = __expf(v.x - m) + __expf(v.y - m) + __expf(v.z - m) + __expf(v.w - m);
    #pragma unroll
    for (int off = 8; off >= 1; off >>= 1) s += __shfl_xor(s, off);
    if (q == 0) atomicAdd(&sumlse[b], (double)(m + __logf(s)));
}

// ---------------- Kernel B: fwd+bwd recursion, 2 waves per example ---------

#define LOADM(E, TB, DIRSGN)                                                    \
    do {                                                                        \
        _Pragma("unroll")                                                       \
        for (int k_ = 0; k_ < CH; ++k_) {                                       \
            int tt_ = (TB) + (DIRSGN) * k_;                                     \
            if (tt_ < 0) tt_ = 0;                                               \
            if (tt_ > tf) tt_ = tf;                                             \
            size_t o_ = (size_t)tt_ * VV;                                       \
            _Pragma("unroll")                                                   \
            for (int i_ = 0; i_ < 5; ++i_) E[i_][k_] = gp[i_][o_];              \
        }                                                                       \
    } while (0)

#define PROCF(E, STEP0, MASKED)                                                 \
    do {                                                                        \
        _Pragma("unroll")                                                       \
        for (int k_ = 0; k_ < CH; ++k_) {                                       \
            double e_[5];                                                       \
            _Pragma("unroll")                                                   \
            for (int i_ = 0; i_ < 5; ++i_)                                      \
                e_[i_] = (double)__builtin_amdgcn_exp2f(E[i_][k_] * L2E);       \
            double pm1_ = __shfl_up(p[4], 1);                                   \
            double pm2_ = __shfl_up(p[3], 1);                                   \
            if (lane == 0) { pm1_ = 0.0; pm2_ = 0.0; }                          \
            double n0_ = e_[0] * (p[0] + pm1_ + skd[0] * pm2_);                 \
            double n1_ = e_[1] * (p[1] + p[0] + skd[1] * pm1_);                 \
            double n2_ = e_[2] * (p[2] + p[1] + skd[2] * p[0]);                 \
            double n3_ = e_[3] * (p[3] + p[2] + skd[3] * p[1]);                 \
            double n4_ = e_[4] * (p[4] + p[3] + skd[4] * p[2]);                 \
            if (MASKED) {                                                       \
                bool act_ = ((STEP0) + k_) < nst_;                              \
                p[0] = act_ ? n0_ : p[0]; p[1] = act_ ? n1_ : p[1];             \
                p[2] = act_ ? n2_ : p[2]; p[3] = act_ ? n3_ : p[3];             \
                p[4] = act_ ? n4_ : p[4];                                       \
            } else {                                                            \
                p[0] = n0_; p[1] = n1_; p[2] = n2_; p[3] = n3_; p[4] = n4_;     \
            }                                                                   \
        }                                                                       \
    } while (0)

#define PROCB(E, STEP0, MASKED)                                                 \
    do {                                                                        \
        _Pragma("unroll")                                                       \
        for (int k_ = 0; k_ < CH; ++k_) {                                       \
            double u_[5];                                                       \
            _Pragma("unroll")                                                   \
            for (int i_ = 0; i_ < 5; ++i_)                                      \
                u_[i_] = p[i_] * (double)__builtin_amdgcn_exp2f(E[i_][k_] * L2E); \
            double u5_ = __shfl_down(u_[0], 1);                                 \
            double u6_ = __shfl_down(u_[1], 1);                                 \
            if (lane == 63) { u5_ = 0.0; u6_ = 0.0; }                           \
            double n0_ = u_[0] + u_[1] + skd[2] * u_[2];                        \
            double n1_ = u_[1] + u_[2] + skd[3] * u_[3];                        \
            double n2_ = u_[2] + u_[3] + skd[4] * u_[4];                        \
            double n3_ = u_[3] + u_[4] + skd[5] * u5_;                          \
            double n4_ = u_[4] + u5_ + skd[6] * u6_;                            \
            if (MASKED) {                                                       \
                bool act_ = ((STEP0) + k_) < nst_;                              \
                p[0] = act_ ? n0_ : p[0]; p[1] = act_ ? n1_ : p[1];             \
                p[2] = act_ ? n2_ : p[2]; p[3] = act_ ? n3_ : p[3];             \
                p[4] = act_ ? n4_ : p[4];                                       \
            } else {                                                            \
                p[0] = n0_; p[1] = n1_; p[2] = n2_; p[3] = n3_; p[4] = n4_;     \
            }                                                                   \
        }                                                                       \
    } while (0)

#define RENORM()                                                                \
    do {                                                                        \
        double mx_ = fmax(fmax(fmax(p[0], p[1]), fmax(p[2], p[3])), p[4]);      \
        int ex_ = (__double2hiint(mx_) >> 20) & 0x7ff;                          \
        _Pragma("unroll")                                                       \
        for (int o_ = 32; o_ >= 1; o_ >>= 1) {                                  \
            int t_ = __shfl_xor(ex_, o_);                                       \
            ex_ = t_ > ex_ ? t_ : ex_;                                          \
        }                                                                       \
        Cexp += ex_ - 1023;                                                     \
        double r_ = __hiloint2double((2046 - ex_) << 20, 0);                    \
        _Pragma("unroll")                                                       \
        for (int i_ = 0; i_ < 5; ++i_) p[i_] *= r_;                             \
    } while (0)

__global__ __launch_bounds__(128) void ctc_kernel(const float* __restrict__ lgall,
                                                  const int* __restrict__ audio_len,
                                                  const int* __restrict__ labels,
                                                  const double* __restrict__ sumlse,
                                                  float* __restrict__ out,
                                                  int B, int T, int L) {
    const int b = blockIdx.x;
    const int tid = threadIdx.x;
    const int lane = tid & 63;
    const int wid = tid >> 6;
    const int S = 2 * L + 1;
    const float* lg = lgall + (size_t)b * T * VV;

    int al = audio_len[b];
    int Tb = ((al + 128) >> 7) >> 1;
    if (Tb < 1) Tb = 1;
    if (Tb > T) Tb = T;
    const int tf = Tb - 1;
    const int mid = tf >> 1;   // fwd steps: t=1..mid ; bwd steps: t=tf..mid+1

    __shared__ int lab_sh[152];
    __shared__ double beta_sh[324];
    __shared__ double sumlse_sh;
    __shared__ int cexpb_sh;

    for (int k = tid; k < L; k += 128) lab_sh[k] = labels[b * L + k];
    __syncthreads();

    int cnt = 0;
    for (int k = lane; k < L; k += 64) cnt += (lab_sh[k] >= 0) ? 1 : 0;
    #pragma unroll
    for (int off = 32; off >= 1; off >>= 1) cnt += __shfl_xor(cnt, off);
    const int s_last = 2 * cnt;

    // per-state symbols (states 5*lane+i) and skip flags (need i up to 6 for bwd)
    int sym[5];
    double skd[7];
    #pragma unroll
    for (int i = 0; i < 7; ++i) {
        int s = lane * 5 + i;
        int sy = 0;
        double sk = 0.0;
        if (s < S && (s & 1)) {
            int lv = lab_sh[s >> 1];
            sy = lv < 0 ? 0 : lv;
            if (s >= 3 && sy != 0) {
                int lv2 = lab_sh[(s >> 1) - 1];
                int s2 = lv2 < 0 ? 0 : lv2;
                sk = (sy != s2) ? 1.0 : 0.0;
            }
        }
        if (i < 5) sym[i] = sy;
        skd[i] = sk;
    }

    const float* gp[5];
    #pragma unroll
    for (int i = 0; i < 5; ++i) gp[i] = lg + sym[i];

    double p[5];
    int Cexp = 0;

    if (wid == 0) {
        // ---------------- forward: alpha ----------------
        {   // t = 0 init
            float e0[5];
            #pragma unroll
            for (int i = 0; i < 5; ++i) e0[i] = gp[i][0];
            #pragma unroll
            for (int i = 0; i < 5; ++i) {
                int s = lane * 5 + i;
                p[i] = (s <= 1) ? (double)__builtin_amdgcn_exp2f(e0[i] * L2E) : 0.0;
            }
        }
        const int nst_ = mid;
        if (nst_ > 0) {
            const int nch = (nst_ + CH - 1) / CH;
            float eA[5][CH], eB[5][CH];
            LOADM(eA, 1, +1);
            int base = 1, c = 0, step0 = 0;
            for (;;) {
                if (c + 1 < nch) LOADM(eB, base + CH, +1);
                if (c == nch - 1) { PROCF(eA, step0, 1); break; }
                PROCF(eA, step0, 0);
                ++c; step0 += CH; base += CH;
                if ((c & 3) == 0) RENORM();
                if (c + 1 < nch) LOADM(eA, base + CH, +1);
                if (c == nch - 1) { PROCF(eB, step0, 1); break; }
                PROCF(eB, step0, 0);
                ++c; step0 += CH; base += CH;
                if ((c & 3) == 0) RENORM();
            }
        }
        RENORM();   // keep magnitudes safe for the dot product
    } else {
        // ---------------- backward: beta ----------------
        #pragma unroll
        for (int i = 0; i < 5; ++i) {
            int s = lane * 5 + i;
            p[i] = (s == s_last || s == s_last - 1) ? 1.0 : 0.0;
        }
        const int nst_ = tf - mid;
        if (nst_ > 0) {
            const int nch = (nst_ + CH - 1) / CH;
            float eA[5][CH], eB[5][CH];
            LOADM(eA, tf, -1);
            int base = tf, c = 0, step0 = 0;
            for (;;) {
                if (c + 1 < nch) LOADM(eB, base - CH, -1);
                if (c == nch - 1) { PROCB(eA, step0, 1); break; }
                PROCB(eA, step0, 0);
                ++c; step0 += CH; base -= CH;
                if ((c & 3) == 0) RENORM();
                if (c + 1 < nch) LOADM(eA, base - CH, -1);
                if (c == nch - 1) { PROCB(eB, step0, 1); break; }
                PROCB(eB, step0, 0);
                ++c; step0 += CH; base -= CH;
                if ((c & 3) == 0) RENORM();
            }
        }
        RENORM();
        #pragma unroll
        for (int i = 0; i < 5; ++i) beta_sh[lane * 5 + i] = p[i];
        if (lane == 0) { cexpb_sh = Cexp; sumlse_sh = sumlse[b]; }
    }
    __syncthreads();

    if (wid == 0) {
        double dot = 0.0;
        #pragma unroll
        for (int i = 0; i < 5; ++i) dot += p[i] * beta_sh[lane * 5 + i];
        #pragma unroll
        for (int o = 32; o >= 1; o >>= 1) dot += __shfl_xor(dot, o);
        if (lane == 0) {
            double lp = log(dot) + (double)(Cexp + cexpb_sh) * LN2D - sumlse_sh;
            atomicAdd(out, (float)(-lp / (double)B));
        }
    }
}

extern "C" void kernel_launch(void* const* d_in, const int* in_sizes, int n_in,
                              void* d_out, int out_size, void* d_ws, size_t ws_size,
                              hipStream_t stream) {
    const float* logits = (const float*)d_in[0];
    const int* audio = (const int*)d_in[1];
    const int* labels = (const int*)d_in[2];
    float* out = (float*)d_out;

    int B = in_sizes[1];
    int L = in_sizes[2] / B;
    int T = in_sizes[0] / (B * VV);

    double* sumlse = (double*)d_ws;   // B doubles
    hipMemsetAsync(sumlse, 0, (size_t)B * sizeof(double), stream);

    dim3 gA((T * 16 + 255) / 256, B);
    lse_kernel<<<gA, 256, 0, stream>>>((const float4*)logits, audio, sumlse, out, T);
    ctc_kernel<<<B, 128, 0, stream>>>(logits, audio, labels, sumlse, out, B, T, L);
}